// Round 1
// baseline (157.775 us; speedup 1.0000x reference)
//
#include <hip/hip_runtime.h>
#include <vector>
#include <cmath>
#include <cstdint>

// ---------------------------------------------------------------------------
// Sparse Clebsch-Gordan tensor product, LMAX=5, TAUS=16, BATCH=256.
//
// Decomposition: one "job" per (l, m, pair(l1,l2)) in exact reference output
// order. Each job produces 16x16 = 256 complex outputs (i over tau1, j over
// tau2), each a sum over m1 of cg(l1,m1,l2,m-m1;l,m) * F1[x,i] * F2[y,j]
// (complex multiply). 457 jobs total; out_off = jobidx*256.
// Write-bound kernel: 239.6 MB output vs 1.18 MB input.
// ---------------------------------------------------------------------------

#define LMAXV 5
#define NTAU 16

static const int CUMT[7] = {0, 16, 64, 144, 256, 400, 576};
constexpr int F_ROWS   = 576;   // complex rows per batch
constexpr int NBATCH   = 256;
constexpr int BPB      = 8;     // batches per block

struct Job { int x_base; int y_base; int count; int coeff_off; int out_off; };

// ------------------------- host-side CG table build ------------------------

static double factd(int n) { double r = 1.0; for (int i = 2; i <= n; ++i) r *= (double)i; return r; }

static double cg_coef(int j1, int m1, int j2, int m2, int j, int m) {
    if (m1 + m2 != m) return 0.0;
    double pref = std::sqrt((2.0 * j + 1.0) * factd(j + j1 - j2) * factd(j - j1 + j2) *
                            factd(j1 + j2 - j) / factd(j1 + j2 + j + 1));
    pref *= std::sqrt(factd(j + m) * factd(j - m) * factd(j1 - m1) * factd(j1 + m1) *
                      factd(j2 - m2) * factd(j2 + m2));
    int kmin = std::max(0, std::max(j2 - j - m1, j1 + m2 - j));
    int kmax = std::min(j1 + j2 - j, std::min(j1 - m1, j2 + m2));
    double s = 0.0;
    for (int k = kmin; k <= kmax; ++k) {
        s += ((k & 1) ? -1.0 : 1.0) /
             (factd(k) * factd(j1 + j2 - j - k) * factd(j1 - m1 - k) * factd(j2 + m2 - k) *
              factd(j - j2 + m1 + k) * factd(j - j1 - m2 + k));
    }
    return pref * s;
}

struct Tables { std::vector<Job> jobs; std::vector<float> coeffs; };

static const Tables& get_tables() {
    static Tables t = []() {
        Tables t;
        int jobidx = 0;
        for (int l = 0; l <= LMAXV; ++l) {
            for (int m_idx = 0; m_idx < 2 * l + 1; ++m_idx) {
                int m = m_idx - l;
                // pairs in PAIRS order for this l: l1 asc, l2 in [l1..LMAX]
                for (int l1 = 0; l1 <= LMAXV; ++l1) {
                    for (int l2 = l1; l2 <= LMAXV; ++l2) {
                        if (!(std::abs(l1 - l2) <= l && l <= l1 + l2)) continue;
                        int lo = std::max(-l1, m - l2), hi = std::min(l1, m + l2);
                        Job jb;
                        jb.count     = hi - lo + 1;                      // <= 11
                        jb.x_base    = CUMT[l1] + (lo + l1) * NTAU;      // row of F1 at m1=lo
                        jb.y_base    = CUMT[l2] + (m - lo + l2) * NTAU;  // row of F2 at m2=m-lo
                        jb.coeff_off = (int)t.coeffs.size();
                        jb.out_off   = jobidx * 256;
                        for (int m1 = lo; m1 <= hi; ++m1)
                            t.coeffs.push_back((float)cg_coef(l1, m1, l2, m - m1, l, m));
                        t.jobs.push_back(jb);
                        ++jobidx;
                    }
                }
            }
        }
        return t;
    }();
    return t;
}

// --------------------------------- kernel ----------------------------------

__global__ __launch_bounds__(256) void cg_tp_kernel(
    const float2* __restrict__ Fs, float2* __restrict__ out,
    const Job* __restrict__ jobs, const float* __restrict__ coeffs,
    int out_per_batch)
{
    const int jid = blockIdx.x / (NBATCH / BPB);
    const int bg  = blockIdx.x % (NBATCH / BPB);
    const Job jb  = jobs[jid];

    __shared__ float sc[16];
    if (threadIdx.x < 16) {
        int k = threadIdx.x;
        sc[k] = (k < jb.count) ? coeffs[jb.coeff_off + k] : 0.0f;
    }
    __syncthreads();

    const int i   = threadIdx.x >> 4;   // tau1 channel
    const int j   = threadIdx.x & 15;   // tau2 channel
    const int xr0 = jb.x_base + i;
    const int yr0 = jb.y_base + j;
    const int cnt = jb.count;

    #pragma unroll
    for (int bb = 0; bb < BPB; ++bb) {
        const int b = bg * BPB + bb;
        const float2* __restrict__ F = Fs + (size_t)b * F_ROWS;
        float aR = 0.0f, aI = 0.0f;
        int xr = xr0, yr = yr0;
        for (int k = 0; k < cnt; ++k) {
            const float  c = sc[k];
            const float2 a = F[xr];   // F1[x, i]  (complex)
            const float2 v = F[yr];   // F2[y, j]  (complex)
            aR += c * (a.x * v.x - a.y * v.y);
            aI += c * (a.x * v.y + a.y * v.x);
            xr += NTAU; yr -= NTAU;
        }
        out[(size_t)b * out_per_batch + jb.out_off + threadIdx.x] = make_float2(aR, aI);
    }
}

// ------------------------------ entry point --------------------------------

extern "C" void kernel_launch(void* const* d_in, const int* in_sizes, int n_in,
                              void* d_out, int out_size, void* d_ws, size_t ws_size,
                              hipStream_t stream) {
    const Tables& t = get_tables();

    char*  ws       = (char*)d_ws;
    Job*   d_jobs   = (Job*)ws;
    size_t jbytes   = t.jobs.size() * sizeof(Job);
    size_t coff     = (jbytes + 255) & ~(size_t)255;
    float* d_coeffs = (float*)(ws + coff);

    hipMemcpyAsync(d_jobs, t.jobs.data(), jbytes, hipMemcpyHostToDevice, stream);
    hipMemcpyAsync(d_coeffs, t.coeffs.data(), t.coeffs.size() * sizeof(float),
                   hipMemcpyHostToDevice, stream);

    const float2* Fs  = (const float2*)d_in[0];
    float2*       out = (float2*)d_out;
    const int out_per_batch = out_size / (NBATCH * 2);   // complex elems per batch

    const int nblocks = (int)t.jobs.size() * (NBATCH / BPB);
    cg_tp_kernel<<<nblocks, 256, 0, stream>>>(Fs, out, d_jobs, d_coeffs, out_per_batch);
}

// Round 2
// 154.749 us; speedup vs baseline: 1.0196x; 1.0196x over previous
//
#include <hip/hip_runtime.h>
#include <vector>
#include <cmath>
#include <cstdint>

// ---------------------------------------------------------------------------
// Sparse Clebsch-Gordan tensor product, LMAX=5, TAUS=16, BATCH=256.
//
// One "job" per (l, m, pair(l1,l2)) in exact reference output order; each job
// produces 16x16=256 contiguous complex outputs per batch. 457 jobs.
// R2: loop interchange (k outer, 8 batches inner-unrolled) for 16 independent
// loads in flight per k-step; non-temporal output stores.
// ---------------------------------------------------------------------------

#define LMAXV 5
#define NTAU 16

static const int CUMT[7] = {0, 16, 64, 144, 256, 400, 576};
constexpr int F_ROWS   = 576;   // complex rows per batch
constexpr int NBATCH   = 256;
constexpr int BPB      = 8;     // batches per block

struct Job { int x_base; int y_base; int count; int coeff_off; int out_off; };

typedef float f32x2 __attribute__((ext_vector_type(2)));

// ------------------------- host-side CG table build ------------------------

static double factd(int n) { double r = 1.0; for (int i = 2; i <= n; ++i) r *= (double)i; return r; }

static double cg_coef(int j1, int m1, int j2, int m2, int j, int m) {
    if (m1 + m2 != m) return 0.0;
    double pref = std::sqrt((2.0 * j + 1.0) * factd(j + j1 - j2) * factd(j - j1 + j2) *
                            factd(j1 + j2 - j) / factd(j1 + j2 + j + 1));
    pref *= std::sqrt(factd(j + m) * factd(j - m) * factd(j1 - m1) * factd(j1 + m1) *
                      factd(j2 - m2) * factd(j2 + m2));
    int kmin = std::max(0, std::max(j2 - j - m1, j1 + m2 - j));
    int kmax = std::min(j1 + j2 - j, std::min(j1 - m1, j2 + m2));
    double s = 0.0;
    for (int k = kmin; k <= kmax; ++k) {
        s += ((k & 1) ? -1.0 : 1.0) /
             (factd(k) * factd(j1 + j2 - j - k) * factd(j1 - m1 - k) * factd(j2 + m2 - k) *
              factd(j - j2 + m1 + k) * factd(j - j1 - m2 + k));
    }
    return pref * s;
}

struct Tables { std::vector<Job> jobs; std::vector<float> coeffs; };

static const Tables& get_tables() {
    static Tables t = []() {
        Tables t;
        int jobidx = 0;
        for (int l = 0; l <= LMAXV; ++l) {
            for (int m_idx = 0; m_idx < 2 * l + 1; ++m_idx) {
                int m = m_idx - l;
                for (int l1 = 0; l1 <= LMAXV; ++l1) {
                    for (int l2 = l1; l2 <= LMAXV; ++l2) {
                        if (!(std::abs(l1 - l2) <= l && l <= l1 + l2)) continue;
                        int lo = std::max(-l1, m - l2), hi = std::min(l1, m + l2);
                        Job jb;
                        jb.count     = hi - lo + 1;                      // <= 11
                        jb.x_base    = CUMT[l1] + (lo + l1) * NTAU;      // F1 row at m1=lo
                        jb.y_base    = CUMT[l2] + (m - lo + l2) * NTAU;  // F2 row at m2=m-lo
                        jb.coeff_off = (int)t.coeffs.size();
                        jb.out_off   = jobidx * 256;
                        for (int m1 = lo; m1 <= hi; ++m1)
                            t.coeffs.push_back((float)cg_coef(l1, m1, l2, m - m1, l, m));
                        t.jobs.push_back(jb);
                        ++jobidx;
                    }
                }
            }
        }
        return t;
    }();
    return t;
}

// --------------------------------- kernel ----------------------------------

__global__ __launch_bounds__(256) void cg_tp_kernel(
    const float2* __restrict__ Fs, float2* __restrict__ out,
    const Job* __restrict__ jobs, const float* __restrict__ coeffs,
    int out_per_batch)
{
    const int jid = blockIdx.x / (NBATCH / BPB);
    const int bg  = blockIdx.x % (NBATCH / BPB);
    const Job jb  = jobs[jid];

    __shared__ float sc[16];
    if (threadIdx.x < 16) {
        int k = threadIdx.x;
        sc[k] = (k < jb.count) ? coeffs[jb.coeff_off + k] : 0.0f;
    }
    __syncthreads();

    const int i   = threadIdx.x >> 4;   // tau1 channel
    const int j   = threadIdx.x & 15;   // tau2 channel
    const int cnt = jb.count;
    const int b0  = bg * BPB;

    // per-thread base rows (complex-element index into Fs)
    const long x0 = (long)jb.x_base + i;   // + k*16 per term
    const long y0 = (long)jb.y_base + j;   // - k*16 per term

    float aR[BPB], aI[BPB];
    #pragma unroll
    for (int bb = 0; bb < BPB; ++bb) { aR[bb] = 0.0f; aI[bb] = 0.0f; }

    for (int k = 0; k < cnt; ++k) {
        const float c  = sc[k];
        const long  xr = x0 + (long)k * NTAU;
        const long  yr = y0 - (long)k * NTAU;
        float2 a[BPB], v[BPB];
        #pragma unroll
        for (int bb = 0; bb < BPB; ++bb) {
            const long boff = (long)(b0 + bb) * F_ROWS;
            a[bb] = Fs[boff + xr];
            v[bb] = Fs[boff + yr];
        }
        #pragma unroll
        for (int bb = 0; bb < BPB; ++bb) {
            const float tR = a[bb].x * v[bb].x - a[bb].y * v[bb].y;
            const float tI = a[bb].x * v[bb].y + a[bb].y * v[bb].x;
            aR[bb] = fmaf(c, tR, aR[bb]);
            aI[bb] = fmaf(c, tI, aI[bb]);
        }
    }

    #pragma unroll
    for (int bb = 0; bb < BPB; ++bb) {
        const long b = b0 + bb;
        f32x2 val; val.x = aR[bb]; val.y = aI[bb];
        f32x2* p = (f32x2*)(out + (size_t)b * out_per_batch + jb.out_off + threadIdx.x);
        __builtin_nontemporal_store(val, p);
    }
}

// ------------------------------ entry point --------------------------------

extern "C" void kernel_launch(void* const* d_in, const int* in_sizes, int n_in,
                              void* d_out, int out_size, void* d_ws, size_t ws_size,
                              hipStream_t stream) {
    const Tables& t = get_tables();

    char*  ws       = (char*)d_ws;
    Job*   d_jobs   = (Job*)ws;
    size_t jbytes   = t.jobs.size() * sizeof(Job);
    size_t coff     = (jbytes + 255) & ~(size_t)255;
    float* d_coeffs = (float*)(ws + coff);

    hipMemcpyAsync(d_jobs, t.jobs.data(), jbytes, hipMemcpyHostToDevice, stream);
    hipMemcpyAsync(d_coeffs, t.coeffs.data(), t.coeffs.size() * sizeof(float),
                   hipMemcpyHostToDevice, stream);

    const float2* Fs  = (const float2*)d_in[0];
    float2*       out = (float2*)d_out;
    const int out_per_batch = out_size / (NBATCH * 2);   // complex elems per batch

    const int nblocks = (int)t.jobs.size() * (NBATCH / BPB);
    cg_tp_kernel<<<nblocks, 256, 0, stream>>>(Fs, out, d_jobs, d_coeffs, out_per_batch);
}